// Round 9
// baseline (134.842 us; speedup 1.0000x reference)
//
#include <hip/hip_runtime.h>

#define B_N  16
#define C_IN 1024
#define C_P  512
#define S_SP 1024

// c0 = exp(-2*gamma), gamma = 1e-4
#define C0_CONST 0.9998000199986667f

typedef float f32x4 __attribute__((ext_vector_type(4)));

// ---------------------------------------------------------------------------
// Math (validated, absmax 0.03125):
//   z_c  = C0 * S0_b * R_c,  R_c = sum_p Wz[c][p]
//   S0_b = sum_c wgc[c]*xs[b][c], wgc[c] = sum_o Wg[o][c], xs = spatial rowsum
//   out  = x + GroupNorm(z); z spatially constant -> per-(b,c) scalar add.
//
// SHAPES: Wg is (C_P=512, C_IN=1024); Wz is (C_IN=1024, C_P=512).
//
// TWO kernels (coef_k folded into add_k's prologue):
// K1 red_k  : all input reductions. Weight blocks first (overlap with the
//   4096-block x stream):
//   [0, 64)      Wg colsums: 4 chunks x 128 rows x 16 col-slices of 64
//   [64, 320)    Wz rowsums: one wave per row
//   [320, 4416)  x rowsums: one wave per row
// K2 addc_k : per-block prologue recomputes the batch scalars (24 KB of
//   L2-resident xs/partial/R, deterministic -> bitwise-identical across
//   blocks), then streams 8 rows of out = x + coef(c) with nontemporal
//   stores. 2048 blocks = 8/CU, all co-resident; prologue overlaps
//   grid-wide. Saves one dispatch + one graph gap vs the 3-kernel form.
// ---------------------------------------------------------------------------
__global__ void red_k(const float* __restrict__ x, const float* __restrict__ Wg,
                      const float* __restrict__ Wz, float* __restrict__ xs,
                      float* __restrict__ partial, float* __restrict__ R)
{
    const int bi   = blockIdx.x;
    const int tid  = threadIdx.x;
    const int lane = tid & 63, wv = tid >> 6;

    if (bi >= 320) {
        // ---- x row sums: row = b*1024 + c, 1024 floats per row ----
        const int row = (bi - 320) * 4 + wv;
        const float* src = x + (size_t)row * S_SP;
        float s = 0.f;
#pragma unroll
        for (int j = 0; j < 4; ++j) {
            f32x4 v = *(const f32x4*)(src + j * 256 + lane * 4);
            s += (v[0] + v[1]) + (v[2] + v[3]);
        }
#pragma unroll
        for (int off = 32; off; off >>= 1) s += __shfl_down(s, off);
        if (lane == 0) xs[row] = s;
    } else if (bi < 64) {
        // ---- Wg colsum chunk-partials: 4 chunks x 128 rows (512 total) ----
        __shared__ float s_red[4][64];
        const int c  = (bi & 15) * 64 + lane;
        const int o0 = (bi >> 4) * 128 + wv * 32;     // max 3*128+3*32 = 480
        float a = 0.f;
#pragma unroll 4
        for (int j = 0; j < 32; ++j)                  // o0+j <= 511 < C_P
            a += Wg[(size_t)(o0 + j) * C_IN + c];
        s_red[wv][lane] = a;
        __syncthreads();
        if (wv == 0)
            partial[(bi >> 4) * C_IN + c] =
                (s_red[0][lane] + s_red[1][lane]) + (s_red[2][lane] + s_red[3][lane]);
    } else {
        // ---- Wz row sums: one wave per row, 512 floats, rows 0..1023 ----
        const int r = (bi - 64) * 4 + wv;
        const float* row = Wz + (size_t)r * C_P;
        f32x4 v0 = *(const f32x4*)(row + lane * 8);
        f32x4 v1 = *(const f32x4*)(row + lane * 8 + 4);
        float s = ((v0[0] + v0[1]) + (v0[2] + v0[3])) +
                  ((v1[0] + v1[1]) + (v1[2] + v1[3]));
#pragma unroll
        for (int off = 32; off; off >>= 1) s += __shfl_down(s, off);
        if (lane == 0) R[r] = s;
    }
}

__global__ void addc_k(const float* __restrict__ x, const float* __restrict__ xs,
                       const float* __restrict__ partial, const float* __restrict__ R,
                       const float* __restrict__ gnw, const float* __restrict__ gnb,
                       float* __restrict__ out)
{
    const int tid  = threadIdx.x;
    const int lane = tid & 63, wv = tid >> 6;
    const int r0   = blockIdx.x * 8;          // 8 rows per block, same batch
    const int b    = r0 >> 10;

    // ---- prologue: batch scalars (identical arithmetic to old coef_k) ----
    f32x4 wv4 = {0.f, 0.f, 0.f, 0.f};
#pragma unroll
    for (int q = 0; q < 4; ++q) {
        f32x4 p = *(const f32x4*)(partial + q * C_IN + tid * 4);
        wv4[0] += p[0]; wv4[1] += p[1]; wv4[2] += p[2]; wv4[3] += p[3];
    }
    f32x4 xv4 = *(const f32x4*)(xs + b * C_IN + tid * 4);
    f32x4 rv4 = *(const f32x4*)(R + tid * 4);

    float p0 = wv4[0] * xv4[0] + wv4[1] * xv4[1] + wv4[2] * xv4[2] + wv4[3] * xv4[3];
    float p1 = (rv4[0] + rv4[1]) + (rv4[2] + rv4[3]);
    float p2 = rv4[0] * rv4[0] + rv4[1] * rv4[1] + rv4[2] * rv4[2] + rv4[3] * rv4[3];

#pragma unroll
    for (int off = 32; off; off >>= 1) {
        p0 += __shfl_down(p0, off);
        p1 += __shfl_down(p1, off);
        p2 += __shfl_down(p2, off);
    }
    __shared__ float red[3][4];
    if (lane == 0) { red[0][wv] = p0; red[1][wv] = p1; red[2][wv] = p2; }
    __syncthreads();
    const float S0   = (red[0][0] + red[0][1]) + (red[0][2] + red[0][3]);
    const float Rsum = (red[1][0] + red[1][1]) + (red[1][2] + red[1][3]);
    const float Rsq  = (red[2][0] + red[2][1]) + (red[2][2] + red[2][3]);

    const float K0   = C0_CONST * S0;
    const float Rbar = Rsum * (1.0f / C_IN);
    const float mu   = K0 * Rbar;
    const float var  = K0 * K0 * (Rsq * (1.0f / C_IN) - Rbar * Rbar);
    const float rs   = rsqrtf(var + 1e-5f);

    // ---- stream: out = x + coef(c), 8 rows, NT stores ----
    const f32x4* xv = (const f32x4*)x;
    f32x4*       ov = (f32x4*)out;
#pragma unroll
    for (int r = 0; r < 8; ++r) {
        const int row = r0 + r;
        const int c   = row & (C_IN - 1);     // block-uniform -> scalar loads
        const float coef = (K0 * R[c] - mu) * rs * gnw[c] + gnb[c];
        const int idx = row * 256 + tid;
        f32x4 v = xv[idx];
        f32x4 o;
        o[0] = v[0] + coef; o[1] = v[1] + coef;
        o[2] = v[2] + coef; o[3] = v[3] + coef;
        __builtin_nontemporal_store(o, &ov[idx]);
    }
}

// ---------------------------------------------------------------------------
// Workspace: xs 64 KB @0, partial 16 KB @64K, R 4 KB @80K
// ---------------------------------------------------------------------------
extern "C" void kernel_launch(void* const* d_in, const int* in_sizes, int n_in,
                              void* d_out, int out_size, void* d_ws, size_t ws_size,
                              hipStream_t stream)
{
    (void)in_sizes; (void)n_in; (void)out_size; (void)ws_size;
    const float* x  = (const float*)d_in[0];
    const float* Wg = (const float*)d_in[3];
    const float* Wz = (const float*)d_in[4];
    const float* gw = (const float*)d_in[5];
    const float* gb = (const float*)d_in[6];
    float* out = (float*)d_out;

    char* ws = (char*)d_ws;
    float* xs      = (float*)(ws);
    float* partial = (float*)(ws + 65536);
    float* R       = (float*)(ws + 81920);

    red_k <<<4416, 256, 0, stream>>>(x, Wg, Wz, xs, partial, R);
    addc_k<<<2048, 256, 0, stream>>>(x, xs, partial, R, gw, gb, out);
}